// Round 2
// baseline (353.083 us; speedup 1.0000x reference)
//
#include <hip/hip_runtime.h>
#include <hip/hip_bf16.h>

#define GROUPS 16
#define BSZ    8192
#define CHN    256

using f32x4  = __attribute__((ext_vector_type(4))) float;
using bf16x8 = __attribute__((ext_vector_type(8))) __bf16;

static __device__ __forceinline__ unsigned short f32_bf16(float f) {
    unsigned int u = __builtin_bit_cast(unsigned int, f);
    u = (u + 0x7FFFu + ((u >> 16) & 1u)) >> 16;   // RNE
    return (unsigned short)u;
}
static __device__ __forceinline__ unsigned int pack_bf16x2(float lo, float hi) {
    return (unsigned int)f32_bf16(lo) | ((unsigned int)f32_bf16(hi) << 16);
}
static __device__ __forceinline__ bf16x8 pack8(float4 u, float4 v) {
    uint4 d;
    d.x = pack_bf16x2(u.x, u.y);
    d.y = pack_bf16x2(u.z, u.w);
    d.z = pack_bf16x2(v.x, v.y);
    d.w = pack_bf16x2(v.z, v.w);
    return __builtin_bit_cast(bf16x8, d);
}

// ---------------------------------------------------------------------------
// Kernel B: compose M = H_0 H_1 ... H_255 per group, row-parallel.
// Row r of M: m = e_r; for i: m -= (2/(w_i.w_i)) (m.w_i) w_i.
// Output: Mt[g][c][n] = M[n][c]  (bf16), n = k-dim for the GEMM.
// Changes vs R1: next-window global loads prefetched before the 16-step loop;
// dot product tree-reduced (4 independent partials) to shorten the serial chain.
// ---------------------------------------------------------------------------
__global__ __launch_bounds__(256) void compose_m(const float* __restrict__ weight,
                                                 unsigned short* __restrict__ Mt) {
    __shared__ float wbuf[16 * 260];
    __shared__ float coefbuf[16];

    const int t    = threadIdx.x;
    const int g    = blockIdx.x >> 4;
    const int r0   = (blockIdx.x & 15) * 16;
    const int lane = t & 15;
    const int rg   = (t >> 4) & 3;
    const int wave = t >> 6;
    const int r    = r0 + wave * 4 + rg;

    float4 m4[4];
#pragma unroll
    for (int j = 0; j < 4; ++j) {
        const int cb = 4 * lane + 64 * j;
        m4[j].x = (cb + 0 == r) ? 1.0f : 0.0f;
        m4[j].y = (cb + 1 == r) ? 1.0f : 0.0f;
        m4[j].z = (cb + 2 == r) ? 1.0f : 0.0f;
        m4[j].w = (cb + 3 == r) ? 1.0f : 0.0f;
    }

    const float* wg = weight + (size_t)g * CHN * CHN;
    const int e16 = t & 15;
    const int nb  = t >> 4;

    float ld[16];
#pragma unroll
    for (int k = 0; k < 16; ++k)               // prefetch window 0
        ld[k] = wg[(nb + 16 * k) * CHN + e16];

    for (int iw = 0; iw < 16; ++iw) {
        __syncthreads();                        // prev window fully consumed
#pragma unroll
        for (int k = 0; k < 16; ++k)
            wbuf[e16 * 260 + nb + 16 * k] = ld[k];
        __syncthreads();
        if (iw < 15) {                          // prefetch next window (overlaps steps)
            const int i0 = (iw + 1) * 16;
#pragma unroll
            for (int k = 0; k < 16; ++k)
                ld[k] = wg[(nb + 16 * k) * CHN + i0 + e16];
        }
        {
            const int e = t >> 4;
            float s = 0.0f;
#pragma unroll
            for (int k = 0; k < 16; ++k) {
                const float w = wbuf[e * 260 + lane + 16 * k];
                s += w * w;
            }
            s += __shfl_xor(s, 1);
            s += __shfl_xor(s, 2);
            s += __shfl_xor(s, 4);
            s += __shfl_xor(s, 8);
            if (lane == 0) coefbuf[e] = 2.0f / s;
        }
        __syncthreads();
#pragma unroll
        for (int e = 0; e < 16; ++e) {
            float4 w4[4];
#pragma unroll
            for (int j = 0; j < 4; ++j)
                w4[j] = *(const float4*)&wbuf[e * 260 + 4 * lane + 64 * j];
            // tree-reduced dot: 4 independent partials, then 2-level combine
            float p0 = m4[0].x * w4[0].x + m4[0].y * w4[0].y +
                       m4[0].z * w4[0].z + m4[0].w * w4[0].w;
            float p1 = m4[1].x * w4[1].x + m4[1].y * w4[1].y +
                       m4[1].z * w4[1].z + m4[1].w * w4[1].w;
            float p2 = m4[2].x * w4[2].x + m4[2].y * w4[2].y +
                       m4[2].z * w4[2].z + m4[2].w * w4[2].w;
            float p3 = m4[3].x * w4[3].x + m4[3].y * w4[3].y +
                       m4[3].z * w4[3].z + m4[3].w * w4[3].w;
            float p = (p0 + p1) + (p2 + p3);
            p += __shfl_xor(p, 1);
            p += __shfl_xor(p, 2);
            p += __shfl_xor(p, 4);
            p += __shfl_xor(p, 8);
            const float s = coefbuf[e] * p;
#pragma unroll
            for (int j = 0; j < 4; ++j) {
                m4[j].x -= s * w4[j].x;
                m4[j].y -= s * w4[j].y;
                m4[j].z -= s * w4[j].z;
                m4[j].w -= s * w4[j].w;
            }
        }
    }

    unsigned short* mg = Mt + (size_t)g * CHN * CHN;
#pragma unroll
    for (int j = 0; j < 4; ++j) {
        const int cb = 4 * lane + 64 * j;
        mg[(size_t)(cb + 0) * CHN + r] = f32_bf16(m4[j].x);
        mg[(size_t)(cb + 1) * CHN + r] = f32_bf16(m4[j].y);
        mg[(size_t)(cb + 2) * CHN + r] = f32_bf16(m4[j].z);
        mg[(size_t)(cb + 3) * CHN + r] = f32_bf16(m4[j].w);
    }
}

// ---------------------------------------------------------------------------
// Kernel C (rewritten): out[g] = x[g] @ M[g], NO LDS, NO BARRIERS.
// Each wave owns 32 rows x 256 cols. A-frags loaded straight from global f32
// (8 consecutive k per lane -> 2x float4, fully coalesced), packed to bf16 in
// regs. B-frags loaded straight from Mt (k-contiguous) via dwordx4 — M is
// 128 KB/group, L2-resident; ~512 MB L2 traffic total (~12 TB/s demand, fine).
// Waves fully independent -> pure streaming; HBM floor 256 MB / 6.3 TB/s.
// Block 256 thr = 4 waves; grid 16 groups x 64 row-blocks (128 rows/block).
// ---------------------------------------------------------------------------
__global__ __launch_bounds__(256, 2) void gemm_stream(const float* __restrict__ x,
                                                      const unsigned short* __restrict__ Mt,
                                                      float* __restrict__ out) {
    const int t    = threadIdx.x;
    const int wave = t >> 6;
    const int l    = t & 63;
    const int lm   = l & 15;
    const int q    = l >> 4;
    const int g    = blockIdx.x >> 6;
    const int rb   = blockIdx.x & 63;
    const int r0   = rb * 128 + wave * 32;

    const float*          xg = x  + ((size_t)g * BSZ + r0) * CHN;
    const unsigned short* mg = Mt +  (size_t)g * CHN * CHN;

    f32x4 acc[2][16];
#pragma unroll
    for (int mi = 0; mi < 2; ++mi)
#pragma unroll
        for (int ni = 0; ni < 16; ++ni)
            acc[mi][ni] = (f32x4){0.f, 0.f, 0.f, 0.f};

    const float*          xa0 = xg + (size_t)(lm)      * CHN + q * 8;  // row mi*16+lm
    const float*          xa1 = xg + (size_t)(16 + lm) * CHN + q * 8;
    const unsigned short* mb  = mg + (size_t)lm * CHN + q * 8;         // col ni*16+lm

    for (int kc = 0; kc < 8; ++kc) {
        const int k0 = kc * 32;
        // A: 2 row-tiles x 8 consecutive k (f32), coalesced 128B lines
        const float4 a00 = *(const float4*)(xa0 + k0);
        const float4 a01 = *(const float4*)(xa0 + k0 + 4);
        const float4 a10 = *(const float4*)(xa1 + k0);
        const float4 a11 = *(const float4*)(xa1 + k0 + 4);
        // B: 16 col-tiles, dwordx4 each (L2-resident M)
        uint4 bv[16];
#pragma unroll
        for (int ni = 0; ni < 16; ++ni)
            bv[ni] = *(const uint4*)(mb + (size_t)ni * 16 * CHN + k0);

        const bf16x8 a0 = pack8(a00, a01);
        const bf16x8 a1 = pack8(a10, a11);
#pragma unroll
        for (int ni = 0; ni < 16; ++ni) {
            const bf16x8 b = __builtin_bit_cast(bf16x8, bv[ni]);
            acc[0][ni] = __builtin_amdgcn_mfma_f32_16x16x32_bf16(a0, b, acc[0][ni], 0, 0, 0);
            acc[1][ni] = __builtin_amdgcn_mfma_f32_16x16x32_bf16(a1, b, acc[1][ni], 0, 0, 0);
        }
    }

    // epilogue: D layout col = lane&15, row = (lane>>4)*4 + reg
    float* og = out + ((size_t)g * BSZ + r0) * CHN;
#pragma unroll
    for (int mi = 0; mi < 2; ++mi) {
#pragma unroll
        for (int ni = 0; ni < 16; ++ni) {
            const int col = ni * 16 + lm;
#pragma unroll
            for (int reg = 0; reg < 4; ++reg) {
                const int row = mi * 16 + q * 4 + reg;
                og[(size_t)row * CHN + col] = acc[mi][ni][reg];
            }
        }
    }
}

extern "C" void kernel_launch(void* const* d_in, const int* in_sizes, int n_in,
                              void* d_out, int out_size, void* d_ws, size_t ws_size,
                              hipStream_t stream) {
    const float* x = (const float*)d_in[0];
    const float* w = (const float*)d_in[1];
    float* out = (float*)d_out;
    unsigned short* Mt = (unsigned short*)d_ws;   // 16*256*256 bf16 = 2 MB

    hipLaunchKernelGGL(compose_m,   dim3(GROUPS * 16), dim3(256), 0, stream, w, Mt);
    hipLaunchKernelGGL(gemm_stream, dim3(GROUPS * 64), dim3(256), 0, stream, x, Mt, out);
}